// Round 1
// baseline (5414.658 us; speedup 1.0000x reference)
//
#include <hip/hip_runtime.h>

// DRL4TSP pointer-network decoder, fully fused single persistent kernel.
//
// Key algebra (see journal): with x[b,s] = (x0,x1,x2,x3) = (static0, static1,
// load-demand, demand):
//   static_hidden[b,h,s] = W_s[h,0]x0 + W_s[h,1]x1 + b_s[h]           (rank-2)
//   base[b,h,s]          = A[h,:]. x[b,s] + biasT[h]                  (rank-4)
//   dec@W_ih^T           = G[g,:].(x0,x1)[ptr] + gbias[g]             (rank-2)
// so base (134 MB) and the dec-side LSTM matmul are never materialized.
// Batch elems are independent -> grid 256 blocks x 8 batch each, 128-step
// scan fused in-kernel, no grid sync. W_hh streamed from L2 each step.

#define H 128
#define S 128
#define NBATCH 2048
#define NB 8               // batch elements per block
#define NT 512             // threads per block (8 waves)
#define NBLK (NBATCH / NB) // 256 blocks
#define BS (NBATCH * S)

// h-state LDS layout: quarter-swizzled, stride 36 (16B-aligned, distinct banks
// across the 4 K-split quarters -> conflict-free ds_read_b128)
#define SHQ 36
#define SHB (4 * SHQ)
#define SHI(bb, h) ((bb) * SHB + (((h) >> 5) * SHQ) + ((h) & 31))
#define QPB 129            // qprime row stride (pad +1)

__device__ __forceinline__ float dot4f(float4 a, float4 b, float c) {
  return fmaf(a.x, b.x, fmaf(a.y, b.y, fmaf(a.z, b.z, fmaf(a.w, b.w, c))));
}
__device__ __forceinline__ float fast_tanh(float x) {
  // tanh(x) = 1 - 2/(e^{2x}+1); exp overflow->inf->tanh=1, underflow->0->-1 (both correct)
  float e = __expf(2.f * x);
  return 1.f - __fdividef(2.f, e + 1.f);
}
__device__ __forceinline__ float fast_sig(float x) {
  return __fdividef(1.f, 1.f + __expf(-x));
}

__global__ __launch_bounds__(NT)
void drl4tsp_fused(const float* __restrict__ st, const float* __restrict__ dyn,
                   const float* __restrict__ W_s, const float* __restrict__ b_s,
                   const float* __restrict__ W_ld, const float* __restrict__ b_ld,
                   const float* __restrict__ W_d, const float* __restrict__ b_d,
                   const float* __restrict__ W_ih, const float* __restrict__ b_ih,
                   const float* __restrict__ W_hh, const float* __restrict__ b_hh,
                   const float* __restrict__ W_pd, const float* __restrict__ b_pd,
                   const float* __restrict__ W_pld, const float* __restrict__ b_pld,
                   const float* __restrict__ W_pq, const float* __restrict__ b_pq,
                   const float* __restrict__ W_pr, const float* __restrict__ b_pr,
                   const float* __restrict__ attn_W, const float* __restrict__ mark,
                   float* __restrict__ out)
{
  __shared__ float4 sX[NB][S];     // folded per-(b,s) inputs (x0,x1,l-d,d)   16 KB
  __shared__ float4 sA[H];         // attention rank-4 weights                 2 KB
  __shared__ float  sAW[H];        // attn_W                                 0.5 KB
  __shared__ float  sQB[H];        // biasT + b_pq                           0.5 KB
  __shared__ float4 sGT[4 * H];    // gate fold (G0, G1, gbias, 0)             8 KB
  __shared__ float  sH[NB * SHB];  // h-state (quarter-swizzled)             4.5 KB
  __shared__ float  sQP[NB * QPB]; // qprime = q + biasT                       4 KB
  __shared__ float  sSelX0[NB];
  __shared__ float  sSelX1[NB];

  const int tid = threadIdx.x;
  const int b0  = blockIdx.x * NB;

  // ---------------- one-time per-block fold tables ----------------
  {
    // Gtable[g] = (W_ih@W_s)[g,0..1], gbias = (W_ih@b_s)[g] + b_ih[g] + b_hh[g]
    const int g = tid;
    const float* wr = W_ih + g * H;
    float g0 = 0.f, g1 = 0.f, gb = 0.f;
    for (int h = 0; h < H; h += 4) {
      float4 w   = *(const float4*)(wr + h);
      float4 s01 = *(const float4*)(W_s + 2 * h);      // Ws[h][0],Ws[h][1],Ws[h+1][0],Ws[h+1][1]
      float4 s23 = *(const float4*)(W_s + 2 * h + 4);
      float4 bs  = *(const float4*)(b_s + h);
      g0 = fmaf(w.x, s01.x, fmaf(w.y, s01.z, fmaf(w.z, s23.x, fmaf(w.w, s23.z, g0))));
      g1 = fmaf(w.x, s01.y, fmaf(w.y, s01.w, fmaf(w.z, s23.y, fmaf(w.w, s23.w, g1))));
      gb = fmaf(w.x, bs.x,  fmaf(w.y, bs.y,  fmaf(w.z, bs.z,  fmaf(w.w, bs.w,  gb))));
    }
    sGT[g] = make_float4(g0, g1, gb + b_ih[g] + b_hh[g], 0.f);
  }
  if (tid < H) {
    // A[h] and combined bias. Note the size-1 dyn channel broadcasts over the
    // two columns of W_ld / W_d -> effective weight = column sum.
    const int h = tid;
    float a0 = 0.f, a1 = 0.f, a2 = 0.f, a3 = 0.f, bt = 0.f;
    for (int j = 0; j < H; ++j) {
      float pr  = W_pr[h * H + j];
      float pld = W_pld[h * H + j];
      float pd  = W_pd[h * H + j];
      float2 wsv = *(const float2*)(W_s + 2 * j);
      float2 wld = *(const float2*)(W_ld + 2 * j);
      float2 wd  = *(const float2*)(W_d + 2 * j);
      a0 = fmaf(pr, wsv.x, a0);
      a1 = fmaf(pr, wsv.y, a1);
      a2 = fmaf(pld, wld.x + wld.y, a2);
      a3 = fmaf(pd,  wd.x + wd.y,  a3);
      bt += pr * b_s[j] + pld * b_ld[j] + pd * b_d[j];
    }
    sA[h]  = make_float4(a0, a1, a2, a3);
    sAW[h] = attn_W[h];
    sQB[h] = bt + b_pr[h] + b_pld[h] + b_pd[h] + b_pq[h];
  }
  for (int i = tid; i < NB * S; i += NT) {
    int bb = i >> 7, s = i & (S - 1);
    int go = (b0 + bb) * 2 * S;
    float x0 = st[go + s];
    float x1 = st[go + S + s];
    float ld = dyn[go + s];
    float dm = dyn[go + S + s];
    sX[bb][s] = make_float4(x0, x1, ld - dm, dm);
  }
  for (int i = tid; i < NB * SHB; i += NT) sH[i] = 0.f;
  if (tid < NB) {
    int go = (b0 + tid) * 2 * S;      // dec0 = static_hidden[:,:,0] -> x at s=0
    sSelX0[tid] = st[go + 0];
    sSelX1[tid] = st[go + S + 0];
  }
  if (blockIdx.x == 0 && tid == 0) out[2 * BS] = mark[0];
  __syncthreads();

  // ---------------- persistent per-thread setup ----------------
  const int gg = tid >> 2, qq = tid & 3;       // matmul: 4-way K-split, partners = adjacent lanes
  const int wv = tid >> 6, lane = tid & 63;    // attention: wave wv <-> batch bb=wv, lane = s / s+64
  const float4 xA = sX[wv][lane];
  const float4 xB = sX[wv][lane + 64];
  const float* wh0 = W_hh + (gg        ) * H + 32 * qq;
  const float* wh1 = W_hh + (gg + H    ) * H + 32 * qq;
  const float* wh2 = W_hh + (gg + 2 * H) * H + 32 * qq;
  const float* wh3 = W_hh + (gg + 3 * H) * H + 32 * qq;
  const float* wqr = W_pq + gg * H + 32 * qq;
  const int shofs = qq * SHQ;
  const int bbA = 2 * qq, bbB = 2 * qq + 1;
  const float4 gt0 = sGT[gg];
  const float4 gt1 = sGT[gg + H];
  const float4 gt2 = sGT[gg + 2 * H];
  const float4 gt3 = sGT[gg + 3 * H];
  const float qb = sQB[gg];
  float cA = 0.f, cB = 0.f;                    // c-state lives in registers

  // ---------------- the 128-step decode scan ----------------
  #pragma unroll 1
  for (int t = 0; t < S; ++t) {
    // ---- Phase A: gates = fold(x[ptr]) + h @ W_hh^T ----
    float acc0[NB], acc1[NB], acc2[NB], acc3[NB];
    #pragma unroll
    for (int bb = 0; bb < NB; ++bb) { acc0[bb] = 0.f; acc1[bb] = 0.f; acc2[bb] = 0.f; acc3[bb] = 0.f; }
    #pragma unroll
    for (int i = 0; i < 8; ++i) {
      float4 w0 = *(const float4*)(wh0 + 4 * i);
      float4 w1 = *(const float4*)(wh1 + 4 * i);
      float4 w2 = *(const float4*)(wh2 + 4 * i);
      float4 w3 = *(const float4*)(wh3 + 4 * i);
      #pragma unroll
      for (int bb = 0; bb < NB; ++bb) {
        float4 hv = *(const float4*)&sH[bb * SHB + shofs + 4 * i];
        acc0[bb] = dot4f(w0, hv, acc0[bb]);
        acc1[bb] = dot4f(w1, hv, acc1[bb]);
        acc2[bb] = dot4f(w2, hv, acc2[bb]);
        acc3[bb] = dot4f(w3, hv, acc3[bb]);
      }
    }
    // reduce the 4-way K-split (partners are lanes xor 1, xor 2)
    #pragma unroll
    for (int bb = 0; bb < NB; ++bb) {
      float v0 = acc0[bb]; v0 += __shfl_xor(v0, 1); v0 += __shfl_xor(v0, 2); acc0[bb] = v0;
      float v1 = acc1[bb]; v1 += __shfl_xor(v1, 1); v1 += __shfl_xor(v1, 2); acc1[bb] = v1;
      float v2 = acc2[bb]; v2 += __shfl_xor(v2, 1); v2 += __shfl_xor(v2, 2); acc2[bb] = v2;
      float v3 = acc3[bb]; v3 += __shfl_xor(v3, 1); v3 += __shfl_xor(v3, 2); acc3[bb] = v3;
    }
    __syncthreads();   // all sH reads done before the h-state update below

    // ---- LSTM activation: this thread owns (bbA,h=gg) and (bbB,h=gg) ----
    {
      const float x0p = sSelX0[bbA], x1p = sSelX1[bbA];
      float gi = acc0[bbA] + fmaf(gt0.x, x0p, fmaf(gt0.y, x1p, gt0.z));
      float gf = acc1[bbA] + fmaf(gt1.x, x0p, fmaf(gt1.y, x1p, gt1.z));
      float gc = acc2[bbA] + fmaf(gt2.x, x0p, fmaf(gt2.y, x1p, gt2.z));
      float go = acc3[bbA] + fmaf(gt3.x, x0p, fmaf(gt3.y, x1p, gt3.z));
      cA = fast_sig(gf) * cA + fast_sig(gi) * fast_tanh(gc);
      sH[SHI(bbA, gg)] = fast_sig(go) * fast_tanh(cA);
    }
    {
      const float x0p = sSelX0[bbB], x1p = sSelX1[bbB];
      float gi = acc0[bbB] + fmaf(gt0.x, x0p, fmaf(gt0.y, x1p, gt0.z));
      float gf = acc1[bbB] + fmaf(gt1.x, x0p, fmaf(gt1.y, x1p, gt1.z));
      float gc = acc2[bbB] + fmaf(gt2.x, x0p, fmaf(gt2.y, x1p, gt2.z));
      float go = acc3[bbB] + fmaf(gt3.x, x0p, fmaf(gt3.y, x1p, gt3.z));
      cB = fast_sig(gf) * cB + fast_sig(gi) * fast_tanh(gc);
      sH[SHI(bbB, gg)] = fast_sig(go) * fast_tanh(cB);
    }
    __syncthreads();

    // ---- Phase B: qprime = h_new @ W_pq^T + (b_pq + biasT) ----
    float qa[NB];
    #pragma unroll
    for (int bb = 0; bb < NB; ++bb) qa[bb] = 0.f;
    #pragma unroll
    for (int i = 0; i < 8; ++i) {
      float4 w = *(const float4*)(wqr + 4 * i);
      #pragma unroll
      for (int bb = 0; bb < NB; ++bb) {
        float4 hv = *(const float4*)&sH[bb * SHB + shofs + 4 * i];
        qa[bb] = dot4f(w, hv, qa[bb]);
      }
    }
    #pragma unroll
    for (int bb = 0; bb < NB; ++bb) {
      float v = qa[bb]; v += __shfl_xor(v, 1); v += __shfl_xor(v, 2); qa[bb] = v;
    }
    sQP[bbA * QPB + gg] = qa[bbA] + qb;
    sQP[bbB * QPB + gg] = qa[bbB] + qb;
    __syncthreads();

    // ---- Phase C: attention + masked softmax + argmax + select ----
    float at0 = 0.f, at1 = 0.f;
    const float* qpp = &sQP[wv * QPB];
    #pragma unroll 4
    for (int h = 0; h < H; ++h) {
      float4 a = sA[h];
      float aw = sAW[h];
      float qp = qpp[h];
      float h0 = fmaf(a.x, xA.x, fmaf(a.y, xA.y, fmaf(a.z, xA.z, fmaf(a.w, xA.w, qp))));
      float h1 = fmaf(a.x, xB.x, fmaf(a.y, xB.y, fmaf(a.z, xB.z, fmaf(a.w, xB.w, qp))));
      at0 = fmaf(aw, fast_tanh(h0), at0);
      at1 = fmaf(aw, fast_tanh(h1), at1);
    }
    // mask2: +10000 for s>=1, +0 for s==0
    float a0 = at0 + ((lane == 0) ? 0.f : 10000.f);
    float a1 = at1 + 10000.f;
    float v; int idx;
    if (a1 > a0) { v = a1; idx = lane + 64; } else { v = a0; idx = lane; }
    #pragma unroll
    for (int m = 1; m < 64; m <<= 1) {           // lexicographic max (v, -idx): first-occurrence argmax
      float ov = __shfl_xor(v, m);
      int   oi = __shfl_xor(idx, m);
      if (ov > v || (ov == v && oi < idx)) { v = ov; idx = oi; }
    }
    float es = __expf(a0 - v) + __expf(a1 - v);  // max prob = 1/sum(exp(a-max))
    #pragma unroll
    for (int m = 1; m < 64; m <<= 1) es += __shfl_xor(es, m);
    if (lane == 0) {
      const int bg = b0 + wv;
      out[bg * S + t]      = (float)idx;         // tour_idx (B,S)
      out[BS + bg * S + t] = -__logf(es);        // tour_logp (B,S)
      float4 xv = sX[wv][idx];                   // dec_{t+1} = static_hidden[:,:,idx]
      sSelX0[wv] = xv.x;
      sSelX1[wv] = xv.y;
    }
    __syncthreads();
  }
}

extern "C" void kernel_launch(void* const* d_in, const int* in_sizes, int n_in,
                              void* d_out, int out_size, void* d_ws, size_t ws_size,
                              hipStream_t stream) {
  const float* st     = (const float*)d_in[0];
  const float* dyn    = (const float*)d_in[1];
  const float* mark   = (const float*)d_in[2];
  const float* W_s    = (const float*)d_in[3];
  const float* b_s    = (const float*)d_in[4];
  const float* W_ld   = (const float*)d_in[5];
  const float* b_ld   = (const float*)d_in[6];
  const float* W_d    = (const float*)d_in[7];
  const float* b_d    = (const float*)d_in[8];
  const float* W_ih   = (const float*)d_in[9];
  const float* b_ih   = (const float*)d_in[10];
  const float* W_hh   = (const float*)d_in[11];
  const float* b_hh   = (const float*)d_in[12];
  const float* W_pd   = (const float*)d_in[13];
  const float* b_pd   = (const float*)d_in[14];
  const float* W_pld  = (const float*)d_in[15];
  const float* b_pld  = (const float*)d_in[16];
  const float* W_pq   = (const float*)d_in[17];
  const float* b_pq   = (const float*)d_in[18];
  const float* W_pr   = (const float*)d_in[19];
  const float* b_pr   = (const float*)d_in[20];
  const float* attn_W = (const float*)d_in[21];
  float* out = (float*)d_out;

  hipLaunchKernelGGL(drl4tsp_fused, dim3(NBLK), dim3(NT), 0, stream,
                     st, dyn, W_s, b_s, W_ld, b_ld, W_d, b_d, W_ih, b_ih,
                     W_hh, b_hh, W_pd, b_pd, W_pld, b_pld, W_pq, b_pq,
                     W_pr, b_pr, attn_W, mark, out);
}

// Round 2
// 3567.967 us; speedup vs baseline: 1.5176x; 1.5176x over previous
//
#include <hip/hip_runtime.h>

// DRL4TSP pointer-network decoder, fully fused single persistent kernel.
// R2: W_hh + W_pq register-resident (R1 rocprof: FETCH_SIZE 8.43 GB ==
// W_hh re-streamed from memory every step at 1.5 TB/s == the whole 5.8 ms).
// Each thread owns a 4-gate x 32-K slice of W_hh (128 floats) + a 32-float
// W_pq slice, loaded once before the scan. __launch_bounds__(512,2) -> 256
// VGPR budget (8 waves/CU unchanged). Gate-fold table moved LDS->regs.
//
// Key algebra (unchanged from R1): with x[b,s] = (static0, static1,
// load-demand, demand):
//   static_hidden[b,h,s] = W_s[h,:].(x0,x1) + b_s[h]                 (rank-2)
//   base[b,h,s]          = A[h,:].x[b,s] + biasT[h]                  (rank-4)
//   dec@W_ih^T           = G[g,:].(x0,x1)[ptr] + gbias[g]            (rank-2)
// so base (134 MB) and the dec-side LSTM matmul are never materialized.

#define H 128
#define S 128
#define NBATCH 2048
#define NB 8               // batch elements per block
#define NT 512             // threads per block (8 waves)
#define NBLK (NBATCH / NB) // 256 blocks
#define BS (NBATCH * S)

// h-state LDS layout: quarter-swizzled, stride 36 (16B-aligned, distinct banks
// across the 4 K-split quarters -> conflict-free ds_read_b128)
#define SHQ 36
#define SHB (4 * SHQ)
#define SHI(bb, h) ((bb) * SHB + (((h) >> 5) * SHQ) + ((h) & 31))
#define QPB 132            // qprime row stride (pad +4, keeps rows 16B-aligned)

__device__ __forceinline__ float dot4f(float4 a, float4 b, float c) {
  return fmaf(a.x, b.x, fmaf(a.y, b.y, fmaf(a.z, b.z, fmaf(a.w, b.w, c))));
}
__device__ __forceinline__ float fast_tanh(float x) {
  // tanh(x) = 1 - 2/(e^{2x}+1); exp overflow->inf->tanh=1, underflow->0->-1 (both correct)
  float e = __expf(2.f * x);
  return 1.f - __fdividef(2.f, e + 1.f);
}
__device__ __forceinline__ float fast_sig(float x) {
  return __fdividef(1.f, 1.f + __expf(-x));
}

__global__ __launch_bounds__(NT, 2)
void drl4tsp_fused(const float* __restrict__ st, const float* __restrict__ dyn,
                   const float* __restrict__ W_s, const float* __restrict__ b_s,
                   const float* __restrict__ W_ld, const float* __restrict__ b_ld,
                   const float* __restrict__ W_d, const float* __restrict__ b_d,
                   const float* __restrict__ W_ih, const float* __restrict__ b_ih,
                   const float* __restrict__ W_hh, const float* __restrict__ b_hh,
                   const float* __restrict__ W_pd, const float* __restrict__ b_pd,
                   const float* __restrict__ W_pld, const float* __restrict__ b_pld,
                   const float* __restrict__ W_pq, const float* __restrict__ b_pq,
                   const float* __restrict__ W_pr, const float* __restrict__ b_pr,
                   const float* __restrict__ attn_W, const float* __restrict__ mark,
                   float* __restrict__ out)
{
  __shared__ float4 sX[NB][S];     // folded per-(b,s) inputs (x0,x1,l-d,d)   16 KB
  __shared__ float4 sA[H];         // attention rank-4 weights                 2 KB
  __shared__ alignas(16) float sAW[H];   // attn_W                           0.5 KB
  __shared__ float  sQB[H];        // biasT + b_pq                           0.5 KB
  __shared__ float  sH[NB * SHB];  // h-state (quarter-swizzled)             4.5 KB
  __shared__ alignas(16) float sQP[NB * QPB]; // qprime = q + biasT            4 KB
  __shared__ float  sSelX0[NB];
  __shared__ float  sSelX1[NB];

  const int tid = threadIdx.x;
  const int b0  = blockIdx.x * NB;
  const int gg = tid >> 2, qq = tid & 3;       // matmul: 4-way K-split, partners = adjacent lanes
  const int wv = tid >> 6, lane = tid & 63;    // attention: wave wv <-> batch bb=wv, lane = s / s+64

  // ---------------- one-time fold tables & staging ----------------
  // Per-thread gate fold for this thread's 4 gate-rows (gg, gg+H, gg+2H, gg+3H):
  //   gt0[g],gt1[g] = (W_ih@W_s)[row,0..1];  gtb[g] = (W_ih@b_s + b_ih + b_hh)[row]
  float gt0v[4], gt1v[4], gtbv[4];
  #pragma unroll
  for (int g = 0; g < 4; ++g) {
    const int row = gg + g * H;
    const float* wr = W_ih + row * H;
    float g0 = 0.f, g1 = 0.f, gb = 0.f;
    for (int h = 0; h < H; h += 4) {
      float4 w   = *(const float4*)(wr + h);
      float4 s01 = *(const float4*)(W_s + 2 * h);      // Ws[h][0],Ws[h][1],Ws[h+1][0],Ws[h+1][1]
      float4 s23 = *(const float4*)(W_s + 2 * h + 4);
      float4 bs  = *(const float4*)(b_s + h);
      g0 = fmaf(w.x, s01.x, fmaf(w.y, s01.z, fmaf(w.z, s23.x, fmaf(w.w, s23.z, g0))));
      g1 = fmaf(w.x, s01.y, fmaf(w.y, s01.w, fmaf(w.z, s23.y, fmaf(w.w, s23.w, g1))));
      gb = fmaf(w.x, bs.x,  fmaf(w.y, bs.y,  fmaf(w.z, bs.z,  fmaf(w.w, bs.w,  gb))));
    }
    gt0v[g] = g0; gt1v[g] = g1; gtbv[g] = gb + b_ih[row] + b_hh[row];
  }
  if (tid < H) {
    // A[h] and combined bias. The size-1 dyn channel broadcasts over the
    // two columns of W_ld / W_d -> effective weight = column sum.
    const int h = tid;
    float a0 = 0.f, a1 = 0.f, a2 = 0.f, a3 = 0.f, bt = 0.f;
    for (int j = 0; j < H; ++j) {
      float pr  = W_pr[h * H + j];
      float pld = W_pld[h * H + j];
      float pd  = W_pd[h * H + j];
      float2 wsv = *(const float2*)(W_s + 2 * j);
      float2 wld = *(const float2*)(W_ld + 2 * j);
      float2 wd  = *(const float2*)(W_d + 2 * j);
      a0 = fmaf(pr, wsv.x, a0);
      a1 = fmaf(pr, wsv.y, a1);
      a2 = fmaf(pld, wld.x + wld.y, a2);
      a3 = fmaf(pd,  wd.x + wd.y,  a3);
      bt += pr * b_s[j] + pld * b_ld[j] + pd * b_d[j];
    }
    sA[h]  = make_float4(a0, a1, a2, a3);
    sAW[h] = attn_W[h];
    sQB[h] = bt + b_pr[h] + b_pld[h] + b_pd[h] + b_pq[h];
  }
  for (int i = tid; i < NB * S; i += NT) {
    int bb = i >> 7, s = i & (S - 1);
    int go = (b0 + bb) * 2 * S;
    float x0 = st[go + s];
    float x1 = st[go + S + s];
    float ld = dyn[go + s];
    float dm = dyn[go + S + s];
    sX[bb][s] = make_float4(x0, x1, ld - dm, dm);
  }
  for (int i = tid; i < NB * SHB; i += NT) sH[i] = 0.f;
  if (tid < NB) {
    int go = (b0 + tid) * 2 * S;      // dec0 = static_hidden[:,:,0] -> x at s=0
    sSelX0[tid] = st[go + 0];
    sSelX1[tid] = st[go + S + 0];
  }
  if (blockIdx.x == 0 && tid == 0) out[2 * BS] = mark[0];

  // ---- register-resident weights: this thread's W_hh / W_pq slices ----
  float4 rW[4][8];                 // 4 gates x 32-K slice  (128 VGPRs)
  #pragma unroll
  for (int g = 0; g < 4; ++g) {
    const float* wr = W_hh + (gg + g * H) * H + 32 * qq;
    #pragma unroll
    for (int k = 0; k < 8; ++k) rW[g][k] = *(const float4*)(wr + 4 * k);
  }
  float4 rQ[8];                    // W_pq slice            (32 VGPRs)
  {
    const float* wr = W_pq + gg * H + 32 * qq;
    #pragma unroll
    for (int k = 0; k < 8; ++k) rQ[k] = *(const float4*)(wr + 4 * k);
  }
  __syncthreads();

  // ---------------- persistent per-thread setup ----------------
  const float4 xA = sX[wv][lane];
  const float4 xB = sX[wv][lane + 64];
  const int shofs = qq * SHQ;
  const int bbA = 2 * qq, bbB = 2 * qq + 1;
  const float qb = sQB[gg];
  float cA = 0.f, cB = 0.f;                    // c-state lives in registers

  // ---------------- the 128-step decode scan ----------------
  #pragma unroll 1
  for (int t = 0; t < S; ++t) {
    // ---- Phase A: gates = fold(x[ptr]) + h @ W_hh^T ----
    // bb processed in two halves of 4 to cap live accumulator registers.
    float gA[4], gB[4];
    #pragma unroll
    for (int half = 0; half < 2; ++half) {
      float a0[4], a1[4], a2[4], a3[4];
      #pragma unroll
      for (int j = 0; j < 4; ++j) { a0[j] = 0.f; a1[j] = 0.f; a2[j] = 0.f; a3[j] = 0.f; }
      #pragma unroll
      for (int i = 0; i < 8; ++i) {
        #pragma unroll
        for (int j = 0; j < 4; ++j) {
          const int bb = half * 4 + j;
          float4 hv = *(const float4*)&sH[bb * SHB + shofs + 4 * i];
          a0[j] = dot4f(rW[0][i], hv, a0[j]);
          a1[j] = dot4f(rW[1][i], hv, a1[j]);
          a2[j] = dot4f(rW[2][i], hv, a2[j]);
          a3[j] = dot4f(rW[3][i], hv, a3[j]);
        }
      }
      #pragma unroll
      for (int j = 0; j < 4; ++j) {
        const int bb = half * 4 + j;
        float v0 = a0[j]; v0 += __shfl_xor(v0, 1); v0 += __shfl_xor(v0, 2);
        float v1 = a1[j]; v1 += __shfl_xor(v1, 1); v1 += __shfl_xor(v1, 2);
        float v2 = a2[j]; v2 += __shfl_xor(v2, 1); v2 += __shfl_xor(v2, 2);
        float v3 = a3[j]; v3 += __shfl_xor(v3, 1); v3 += __shfl_xor(v3, 2);
        if (bb == bbA) { gA[0] = v0; gA[1] = v1; gA[2] = v2; gA[3] = v3; }
        if (bb == bbB) { gB[0] = v0; gB[1] = v1; gB[2] = v2; gB[3] = v3; }
      }
    }
    __syncthreads();   // all sH reads done before the h-state update below

    // ---- LSTM activation: this thread owns (bbA,h=gg) and (bbB,h=gg) ----
    {
      const float x0p = sSelX0[bbA], x1p = sSelX1[bbA];
      float gi = gA[0] + fmaf(gt0v[0], x0p, fmaf(gt1v[0], x1p, gtbv[0]));
      float gf = gA[1] + fmaf(gt0v[1], x0p, fmaf(gt1v[1], x1p, gtbv[1]));
      float gc = gA[2] + fmaf(gt0v[2], x0p, fmaf(gt1v[2], x1p, gtbv[2]));
      float go = gA[3] + fmaf(gt0v[3], x0p, fmaf(gt1v[3], x1p, gtbv[3]));
      cA = fast_sig(gf) * cA + fast_sig(gi) * fast_tanh(gc);
      sH[SHI(bbA, gg)] = fast_sig(go) * fast_tanh(cA);
    }
    {
      const float x0p = sSelX0[bbB], x1p = sSelX1[bbB];
      float gi = gB[0] + fmaf(gt0v[0], x0p, fmaf(gt1v[0], x1p, gtbv[0]));
      float gf = gB[1] + fmaf(gt0v[1], x0p, fmaf(gt1v[1], x1p, gtbv[1]));
      float gc = gB[2] + fmaf(gt0v[2], x0p, fmaf(gt1v[2], x1p, gtbv[2]));
      float go = gB[3] + fmaf(gt0v[3], x0p, fmaf(gt1v[3], x1p, gtbv[3]));
      cB = fast_sig(gf) * cB + fast_sig(gi) * fast_tanh(cB * 0.f + gc);  // same as fast_tanh(gc)
      sH[SHI(bbB, gg)] = fast_sig(go) * fast_tanh(cB);
    }
    __syncthreads();

    // ---- Phase B: qprime = h_new @ W_pq^T + (b_pq + biasT) ----
    float qA, qB;
    #pragma unroll
    for (int half = 0; half < 2; ++half) {
      float qa[4];
      #pragma unroll
      for (int j = 0; j < 4; ++j) qa[j] = 0.f;
      #pragma unroll
      for (int i = 0; i < 8; ++i) {
        #pragma unroll
        for (int j = 0; j < 4; ++j) {
          const int bb = half * 4 + j;
          float4 hv = *(const float4*)&sH[bb * SHB + shofs + 4 * i];
          qa[j] = dot4f(rQ[i], hv, qa[j]);
        }
      }
      #pragma unroll
      for (int j = 0; j < 4; ++j) {
        const int bb = half * 4 + j;
        float v = qa[j]; v += __shfl_xor(v, 1); v += __shfl_xor(v, 2);
        if (bb == bbA) qA = v;
        if (bb == bbB) qB = v;
      }
    }
    sQP[bbA * QPB + gg] = qA + qb;
    sQP[bbB * QPB + gg] = qB + qb;
    __syncthreads();

    // ---- Phase C: attention + masked softmax + argmax + select ----
    float at0 = 0.f, at1 = 0.f;
    const float* qpp = &sQP[wv * QPB];
    #pragma unroll 2
    for (int k = 0; k < 32; ++k) {
      float4 qv = *(const float4*)(qpp + 4 * k);
      float4 aw = *(const float4*)(&sAW[4 * k]);
      float4 a;
      a = sA[4 * k + 0];
      { float h0 = dot4f(a, xA, qv.x), h1 = dot4f(a, xB, qv.x);
        at0 = fmaf(aw.x, fast_tanh(h0), at0); at1 = fmaf(aw.x, fast_tanh(h1), at1); }
      a = sA[4 * k + 1];
      { float h0 = dot4f(a, xA, qv.y), h1 = dot4f(a, xB, qv.y);
        at0 = fmaf(aw.y, fast_tanh(h0), at0); at1 = fmaf(aw.y, fast_tanh(h1), at1); }
      a = sA[4 * k + 2];
      { float h0 = dot4f(a, xA, qv.z), h1 = dot4f(a, xB, qv.z);
        at0 = fmaf(aw.z, fast_tanh(h0), at0); at1 = fmaf(aw.z, fast_tanh(h1), at1); }
      a = sA[4 * k + 3];
      { float h0 = dot4f(a, xA, qv.w), h1 = dot4f(a, xB, qv.w);
        at0 = fmaf(aw.w, fast_tanh(h0), at0); at1 = fmaf(aw.w, fast_tanh(h1), at1); }
    }
    // mask2: +10000 for s>=1, +0 for s==0
    float a0 = at0 + ((lane == 0) ? 0.f : 10000.f);
    float a1 = at1 + 10000.f;
    float v; int idx;
    if (a1 > a0) { v = a1; idx = lane + 64; } else { v = a0; idx = lane; }
    #pragma unroll
    for (int m = 1; m < 64; m <<= 1) {           // lexicographic max (v, -idx): first-occurrence argmax
      float ov = __shfl_xor(v, m);
      int   oi = __shfl_xor(idx, m);
      if (ov > v || (ov == v && oi < idx)) { v = ov; idx = oi; }
    }
    float es = __expf(a0 - v) + __expf(a1 - v);  // max prob = 1/sum(exp(a-max))
    #pragma unroll
    for (int m = 1; m < 64; m <<= 1) es += __shfl_xor(es, m);
    if (lane == 0) {
      const int bg = b0 + wv;
      out[bg * S + t]      = (float)idx;         // tour_idx (B,S)
      out[BS + bg * S + t] = -__logf(es);        // tour_logp (B,S)
      float4 xv = sX[wv][idx];                   // dec_{t+1} = static_hidden[:,:,idx]
      sSelX0[wv] = xv.x;
      sSelX1[wv] = xv.y;
    }
    __syncthreads();
  }
}

extern "C" void kernel_launch(void* const* d_in, const int* in_sizes, int n_in,
                              void* d_out, int out_size, void* d_ws, size_t ws_size,
                              hipStream_t stream) {
  const float* st     = (const float*)d_in[0];
  const float* dyn    = (const float*)d_in[1];
  const float* mark   = (const float*)d_in[2];
  const float* W_s    = (const float*)d_in[3];
  const float* b_s    = (const float*)d_in[4];
  const float* W_ld   = (const float*)d_in[5];
  const float* b_ld   = (const float*)d_in[6];
  const float* W_d    = (const float*)d_in[7];
  const float* b_d    = (const float*)d_in[8];
  const float* W_ih   = (const float*)d_in[9];
  const float* b_ih   = (const float*)d_in[10];
  const float* W_hh   = (const float*)d_in[11];
  const float* b_hh   = (const float*)d_in[12];
  const float* W_pd   = (const float*)d_in[13];
  const float* b_pd   = (const float*)d_in[14];
  const float* W_pld  = (const float*)d_in[15];
  const float* b_pld  = (const float*)d_in[16];
  const float* W_pq   = (const float*)d_in[17];
  const float* b_pq   = (const float*)d_in[18];
  const float* W_pr   = (const float*)d_in[19];
  const float* b_pr   = (const float*)d_in[20];
  const float* attn_W = (const float*)d_in[21];
  float* out = (float*)d_out;

  hipLaunchKernelGGL(drl4tsp_fused, dim3(NBLK), dim3(NT), 0, stream,
                     st, dyn, W_s, b_s, W_ld, b_ld, W_d, b_d, W_ih, b_ih,
                     W_hh, b_hh, W_pd, b_pd, W_pld, b_pld, W_pq, b_pq,
                     W_pr, b_pr, attn_W, mark, out);
}